// Round 13
// baseline (28.021 us; speedup 1.0000x reference)
//
#include <hip/hip_runtime.h>
#include <math.h>

#define IMG    512
#define IMG2   (IMG*IMG)
#define TC     64
#define TR     32
#define ECC    72              // TC + 8 extended columns
#define PITCH  33              // rows per column incl. dump row 32
#define NBATCH 32
#define NBLOCKS ((IMG/TC)*(IMG/TR)*NBATCH)   // 4096
#define NPIX   8388608.0f

typedef unsigned int u32;
typedef float f2 __attribute__((ext_vector_type(2)));

// RNE pack: dst.lo16 = bf16(a), dst.hi16 = bf16(b)
__device__ __forceinline__ u32 pk_bf16(float a, float b) {
    float r;
    asm("v_cvt_pk_bf16_f32 %0, %1, %2" : "=v"(r) : "v"(a), "v"(b));
    return __float_as_uint(r);
}
__device__ __forceinline__ float lo16(u32 x) { return __uint_as_float(x << 16); }
__device__ __forceinline__ float hi16(u32 x) { return __uint_as_float(x & 0xffff0000u); }

__global__ __launch_bounds__(256, 5)
void lncc_main(const float* __restrict__ Tm, const float* __restrict__ Im,
               float* __restrict__ partial)
{
    // 12 B/entry column sums, split so pass-2 column reads are conflict-free:
    //   AB: uint2 {pk(w0,w1), pk(w2,w3)}  -> 2-way banks (free)
    //   Cc: u32   pk(w4,w4)               -> conflict-free
    __shared__ uint2 AB[ECC * PITCH];      // 19,008 B
    __shared__ u32   Cc[ECC * PITCH];      //  9,504 B
    __shared__ float wsum[4];

    const int tid = threadIdx.x;
    const int x0 = blockIdx.x * TC;
    const int y0 = blockIdx.y * TR;
    const size_t base = (size_t)blockIdx.z * IMG2;
    const float* tb = Tm + base;
    const float* ib = Im + base;

    const bool interior = (blockIdx.x - 1u < 6u) & (blockIdx.y - 1u < 14u);

    // ---- Pass 1 (R11-proven): vertical sliding 9-sums; 3 strips x 72 cols ----
    if (tid < 3 * ECC) {
        const int ec    = tid % ECC;
        const int strip = tid / ECC;        // 0,1,2
        const int r0    = strip * 11;       // strip2 writes row 32 = dump slot

        f2 tv_[19];                          // {t, v} per window row

        if (interior) {
            const int off0 = (y0 + r0 - 4) * IMG + (x0 + ec - 4);
            const float* tp = tb + off0;
            const float* ip = ib + off0;
            #pragma unroll
            for (int j = 0; j < 19; ++j) {
                tv_[j].x = tp[j * IMG];
                tv_[j].y = ip[j * IMG];
            }
        } else {
            const int gx   = x0 + ec - 4;
            const float xm = ((unsigned)gx < IMG) ? 1.0f : 0.0f;
            const int gxc  = gx < 0 ? 0 : (gx > IMG - 1 ? IMG - 1 : gx);
            const int Y    = y0 + r0 - 4;
            #pragma unroll
            for (int j = 0; j < 19; ++j) {
                const int gy  = Y + j;
                const float m = ((unsigned)gy < IMG) ? xm : 0.0f;
                const int gyc = gy < 0 ? 0 : (gy > IMG - 1 ? IMG - 1 : gy);
                const int off = (gyc << 9) + gxc;
                tv_[j].x = tb[off] * m;
                tv_[j].y = ib[off] * m;
            }
        }

        f2 s01 = {0.f, 0.f}, s23 = {0.f, 0.f};
        float s4 = 0.f;
        #pragma unroll
        for (int j = 0; j < 19; ++j) {
            const f2 t = tv_[j];
            s01 += t;                        // v_pk_add_f32
            s23 += t * t;                    // v_pk_fma_f32
            s4 = fmaf(t.x, t.y, s4);
            if (j >= 8) {
                const int idx = ec * PITCH + r0 + (j - 8);
                AB[idx] = make_uint2(pk_bf16(s01.x, s01.y), pk_bf16(s23.x, s23.y));
                Cc[idx] = pk_bf16(s4, s4);
                const f2 o = tv_[j - 8];
                s01 -= o;
                s23 -= o * o;
                s4 = fmaf(-o.x, o.y, s4);
            }
        }
    }
    __syncthreads();

    // ---- Pass 2: horizontal sliding 9-sums + score ----
    // CHANGE (R13): burst-load ALL 32 LDS reads of the task into registers
    // first (one latency exposure instead of up to 16), then slide & score
    // purely from registers. Slide re-unpacks eab[k-9] (no ring registers).
    float lsum = 0.f;
    {
        const int row = tid & 31;
        const int b0  = (tid >> 5) * 8 * PITCH + row;

        uint2 eab[16];
        u32   ec_[16];
        #pragma unroll
        for (int k = 0; k < 16; ++k) {
            eab[k] = AB[b0 + k * PITCH];
            ec_[k] = Cc[b0 + k * PITCH];
        }

        f2 W01 = {0.f, 0.f}, W23 = {0.f, 0.f};
        float W4 = 0.f;
        const f2 inv81 = {1.0f / 81.0f, 1.0f / 81.0f};

        #pragma unroll
        for (int k = 0; k < 16; ++k) {
            f2 h01, h23;
            h01.x = lo16(eab[k].x); h01.y = hi16(eab[k].x);
            h23.x = lo16(eab[k].y); h23.y = hi16(eab[k].y);
            W01 += h01; W23 += h23; W4 += hi16(ec_[k]);    // v_pk_add_f32
            if (k >= 8) {
                const f2 tt  = W01 * inv81;                 // pk_mul
                const f2 IJv = W23 - tt * W01;              // pk_fma {I_var, J_var}
                const float cross = fmaf(-tt.x, W01.y, W4);
                const float den   = fmaf(IJv.x, IJv.y, 1e-12f);
                lsum = fmaf(cross, __builtin_amdgcn_rsqf(den), lsum);
                // slide: re-unpack entry k-8 (oldest in window) and subtract
                const int o = k - 8;
                f2 o01, o23;
                o01.x = lo16(eab[o].x); o01.y = hi16(eab[o].x);
                o23.x = lo16(eab[o].y); o23.y = hi16(eab[o].y);
                W01 -= o01; W23 -= o23; W4 -= hi16(ec_[o]);
            }
        }
    }

    // ---- deterministic block reduction ----
    #pragma unroll
    for (int d = 32; d >= 1; d >>= 1) lsum += __shfl_down(lsum, d, 64);
    if ((tid & 63) == 0) wsum[tid >> 6] = lsum;
    __syncthreads();
    if (tid == 0) {
        const int bid = (blockIdx.z * gridDim.y + blockIdx.y) * gridDim.x + blockIdx.x;
        partial[bid] = wsum[0] + wsum[1] + wsum[2] + wsum[3];
    }
}

__global__ __launch_bounds__(256)
void lncc_reduce(const float* __restrict__ partial, float* __restrict__ out)
{
    __shared__ float ws[4];
    const int tid = threadIdx.x;
    const float4* p4 = (const float4*)partial;
    float s = 0.f;
    #pragma unroll
    for (int i = 0; i < NBLOCKS / 1024; ++i) {
        const float4 v = p4[tid + i * 256];
        s += (v.x + v.y) + (v.z + v.w);
    }
    #pragma unroll
    for (int d = 32; d >= 1; d >>= 1) s += __shfl_down(s, d, 64);
    if ((tid & 63) == 0) ws[tid >> 6] = s;
    __syncthreads();
    if (tid == 0) out[0] = 1.0f - (ws[0] + ws[1] + ws[2] + ws[3]) / NPIX;
}

extern "C" void kernel_launch(void* const* d_in, const int* in_sizes, int n_in,
                              void* d_out, int out_size, void* d_ws, size_t ws_size,
                              hipStream_t stream)
{
    (void)in_sizes; (void)n_in; (void)out_size; (void)ws_size;
    const float* Tm = (const float*)d_in[0];   // template
    const float* Im = (const float*)d_in[1];   // image
    float* out  = (float*)d_out;
    float* part = (float*)d_ws;                // NBLOCKS floats of scratch

    dim3 grid(IMG / TC, IMG / TR, NBATCH);     // (8, 16, 32)
    lncc_main<<<grid, 256, 0, stream>>>(Tm, Im, part);
    lncc_reduce<<<1, 256, 0, stream>>>(part, out);
}

// Round 14
// 27.327 us; speedup vs baseline: 1.0254x; 1.0254x over previous
//
#include <hip/hip_runtime.h>
#include <math.h>

#define IMG    512
#define IMG2   (IMG*IMG)
#define TC     64
#define TR     32
#define ECC    72              // TC + 8 extended columns
#define PITCH  33              // rows per column incl. dump row 32
#define NBATCH 32
#define NBLOCKS ((IMG/TC)*(IMG/TR)*NBATCH)   // 4096
#define NPIX   8388608.0f

typedef unsigned int u32;

// RNE pack: dst.lo16 = bf16(a), dst.hi16 = bf16(b)
__device__ __forceinline__ u32 pk_bf16(float a, float b) {
    float r;
    asm("v_cvt_pk_bf16_f32 %0, %1, %2" : "=v"(r) : "v"(a), "v"(b));
    return __float_as_uint(r);
}
__device__ __forceinline__ float lo16(u32 x) { return __uint_as_float(x << 16); }
__device__ __forceinline__ float hi16(u32 x) { return __uint_as_float(x & 0xffff0000u); }

__global__ __launch_bounds__(256, 5)
void lncc_main(const float* __restrict__ Tm, const float* __restrict__ Im,
               float* __restrict__ partial)
{
    // 12 B/entry column sums, split so pass-2 column reads are conflict-free:
    //   AB: uint2 {pk(w0,w1), pk(w2,w3)}  -> 2-way banks (free)
    //   Cc: u32   pk(w4,w4)               -> conflict-free
    // 28.5 KB total -> 5 blocks/CU. Measured best configuration (R7: 27.41 us).
    __shared__ uint2 AB[ECC * PITCH];      // 19,008 B
    __shared__ u32   Cc[ECC * PITCH];      //  9,504 B
    __shared__ float wsum[4];

    const int tid = threadIdx.x;
    const int x0 = blockIdx.x * TC;
    const int y0 = blockIdx.y * TR;
    const size_t base = (size_t)blockIdx.z * IMG2;
    const float* tb = Tm + base;
    const float* ib = Im + base;

    const bool interior = (blockIdx.x - 1u < 6u) & (blockIdx.y - 1u < 14u);

    // ---- Pass 1: vertical sliding 9-sums; 3 strips x 72 columns ----
    if (tid < 3 * ECC) {
        const int ec    = tid % ECC;
        const int strip = tid / ECC;        // 0,1,2
        const int r0    = strip * 11;       // strip2 writes row 32 = dump slot

        float tv_[19], vv_[19];

        if (interior) {
            const int off0 = (y0 + r0 - 4) * IMG + (x0 + ec - 4);
            const float* tp = tb + off0;
            const float* ip = ib + off0;
            #pragma unroll
            for (int j = 0; j < 19; ++j) {
                tv_[j] = tp[j * IMG];
                vv_[j] = ip[j * IMG];
            }
        } else {
            const int gx   = x0 + ec - 4;
            const float xm = ((unsigned)gx < IMG) ? 1.0f : 0.0f;
            const int gxc  = gx < 0 ? 0 : (gx > IMG - 1 ? IMG - 1 : gx);
            const int Y    = y0 + r0 - 4;
            #pragma unroll
            for (int j = 0; j < 19; ++j) {
                const int gy  = Y + j;
                const float m = ((unsigned)gy < IMG) ? xm : 0.0f;
                const int gyc = gy < 0 ? 0 : (gy > IMG - 1 ? IMG - 1 : gy);
                const int off = (gyc << 9) + gxc;
                tv_[j] = tb[off] * m;
                vv_[j] = ib[off] * m;
            }
        }

        float s0 = 0.f, s1 = 0.f, s2 = 0.f, s3 = 0.f, s4 = 0.f;
        #pragma unroll
        for (int j = 0; j < 19; ++j) {
            const float t = tv_[j], v = vv_[j];
            s0 += t; s1 += v;
            s2 = fmaf(t, t, s2); s3 = fmaf(v, v, s3); s4 = fmaf(t, v, s4);
            if (j >= 8) {
                const int idx = ec * PITCH + r0 + (j - 8);
                AB[idx] = make_uint2(pk_bf16(s0, s1), pk_bf16(s2, s3));
                Cc[idx] = pk_bf16(s4, s4);
                const float ot = tv_[j - 8], ov = vv_[j - 8];
                s0 -= ot; s1 -= ov;
                s2 = fmaf(-ot, ot, s2); s3 = fmaf(-ov, ov, s3); s4 = fmaf(-ot, ov, s4);
            }
        }
    }
    __syncthreads();

    // ---- Pass 2: horizontal sliding 9-sums + score; 32 rows x 8 segments ----
    float lsum = 0.f;
    {
        const int row = tid & 31;
        const int b0  = (tid >> 5) * 8 * PITCH + row;
        float W0 = 0.f, W1 = 0.f, W2 = 0.f, W3 = 0.f, W4 = 0.f;
        float r0_[9], r1_[9], r2_[9], r3_[9], r4_[9];   // unpacked ring (named regs)
        const float inv81 = 1.0f / 81.0f;

        #pragma unroll
        for (int k = 0; k < 16; ++k) {
            const uint2 ab = AB[b0 + k * PITCH];
            const u32   c  = Cc[b0 + k * PITCH];
            const float h0 = lo16(ab.x), h1 = hi16(ab.x);
            const float h2 = lo16(ab.y), h3 = hi16(ab.y);
            const float h4 = hi16(c);
            W0 += h0; W1 += h1; W2 += h2; W3 += h3; W4 += h4;
            const int ri = k % 9;
            r0_[ri] = h0; r1_[ri] = h1; r2_[ri] = h2; r3_[ri] = h3; r4_[ri] = h4;
            if (k >= 8) {
                const float t0 = W0 * inv81;
                const float t1 = W1 * inv81;
                const float cross = fmaf(-t0, W1, W4);
                const float Iv    = fmaf(-t0, W0, W2);
                const float Jv    = fmaf(-t1, W1, W3);
                const float den   = fmaf(Iv, Jv, 1e-12f);
                lsum = fmaf(cross, __builtin_amdgcn_rsqf(den), lsum);
                const int o = (k - 8) % 9;
                W0 -= r0_[o]; W1 -= r1_[o]; W2 -= r2_[o]; W3 -= r3_[o]; W4 -= r4_[o];
            }
        }
    }

    // ---- deterministic block reduction ----
    #pragma unroll
    for (int d = 32; d >= 1; d >>= 1) lsum += __shfl_down(lsum, d, 64);
    if ((tid & 63) == 0) wsum[tid >> 6] = lsum;
    __syncthreads();
    if (tid == 0) {
        const int bid = (blockIdx.z * gridDim.y + blockIdx.y) * gridDim.x + blockIdx.x;
        partial[bid] = wsum[0] + wsum[1] + wsum[2] + wsum[3];
    }
}

__global__ __launch_bounds__(256)
void lncc_reduce(const float* __restrict__ partial, float* __restrict__ out)
{
    __shared__ float ws[4];
    const int tid = threadIdx.x;
    const float4* p4 = (const float4*)partial;
    float s = 0.f;
    #pragma unroll
    for (int i = 0; i < NBLOCKS / 1024; ++i) {
        const float4 v = p4[tid + i * 256];
        s += (v.x + v.y) + (v.z + v.w);
    }
    #pragma unroll
    for (int d = 32; d >= 1; d >>= 1) s += __shfl_down(s, d, 64);
    if ((tid & 63) == 0) ws[tid >> 6] = s;
    __syncthreads();
    if (tid == 0) out[0] = 1.0f - (ws[0] + ws[1] + ws[2] + ws[3]) / NPIX;
}

extern "C" void kernel_launch(void* const* d_in, const int* in_sizes, int n_in,
                              void* d_out, int out_size, void* d_ws, size_t ws_size,
                              hipStream_t stream)
{
    (void)in_sizes; (void)n_in; (void)out_size; (void)ws_size;
    const float* Tm = (const float*)d_in[0];   // template
    const float* Im = (const float*)d_in[1];   // image
    float* out  = (float*)d_out;
    float* part = (float*)d_ws;                // NBLOCKS floats of scratch

    dim3 grid(IMG / TC, IMG / TR, NBATCH);     // (8, 16, 32)
    lncc_main<<<grid, 256, 0, stream>>>(Tm, Im, part);
    lncc_reduce<<<1, 256, 0, stream>>>(part, out);
}